// Round 3
// baseline (49.632 us; speedup 1.0000x reference)
//
#include <hip/hip_runtime.h>
#include <cstdint>
#include <cstddef>

#define B_ 32
#define V_ 8
#define S_ 4096
#define E_ 64
#define WIN_ 16
#define STEP_ 4
#define T_ 1020   // len(arange(0, S-WIN, STEP))

typedef __bf16 bf16_t;
typedef bf16_t bf16x8 __attribute__((ext_vector_type(8)));
typedef float f32x4 __attribute__((ext_vector_type(4)));

// ---------------- stage 1 (+ fused W2 prep): ----------------
// e[b][d][s] = floor(sum_v x[b][v][s]*W1[v][d] + b1[d]), bf16, layout [B][E][S].
// Blocks with blockIdx.x==16 instead convert W2 -> W2T[n][f] bf16.
__global__ __launch_bounds__(256) void stage1_kernel(const float* __restrict__ x,
                                                     const float* __restrict__ W1,
                                                     const float* __restrict__ b1,
                                                     const float* __restrict__ W2,
                                                     bf16_t* __restrict__ eb,
                                                     bf16_t* __restrict__ w2t) {
  const int tid = threadIdx.x;
  if (blockIdx.x == 16) {
    // W2T[n][f] = (bf16) W2[f][n]; 65536 elems over 32 y-blocks, 8 per thread
    const int i0 = blockIdx.y * 2048 + tid * 8;
    const int n = i0 >> 10, f0 = i0 & 1023;
    bf16x8 v;
#pragma unroll
    for (int j = 0; j < 8; ++j) v[j] = (bf16_t)W2[(f0 + j) * E_ + n];
    *reinterpret_cast<bf16x8*>(w2t + i0) = v;
    return;
  }
  __shared__ float w1s[V_ * E_];
  __shared__ float b1s[E_];
  __shared__ bf16_t tile[E_ * 256];   // [d][s_local]
  const int b = blockIdx.y;
  const int s0 = blockIdx.x * 256;
  for (int i = tid; i < V_ * E_; i += 256) w1s[i] = W1[i];
  if (tid < E_) b1s[tid] = b1[tid];
  __syncthreads();
  const int s = s0 + tid;
  float xv[V_];
#pragma unroll
  for (int v = 0; v < V_; ++v) xv[v] = x[((size_t)(b * V_ + v) << 12) + s];
  for (int d = 0; d < E_; ++d) {
    float acc = b1s[d];
#pragma unroll
    for (int v = 0; v < V_; ++v) acc += xv[v] * w1s[v * E_ + d];
    tile[d * 256 + tid] = (bf16_t)floorf(acc);
  }
  __syncthreads();
  for (int i = tid; i < E_ * 32; i += 256) {
    const int row = i >> 5, seg = i & 31;
    *reinterpret_cast<bf16x8*>(eb + (((size_t)(b * E_ + row)) << 12) + s0 + seg * 8) =
        *reinterpret_cast<const bf16x8*>(tile + row * 256 + seg * 8);
  }
}

// ---------------- stage 2: tokens[b][t][n] = floor(sum_f flat[b,t,f]*W2[f,n] + b2[n]) ----
// flat[b,t,f] = e[b, f>>4, 4t + (f&15)].  MFMA 16x16x32 bf16.
// Block: 128 thr = 2 waves; tile = 32 tokens x 64 n x 2 batches (mb=2 amortizes B-LDS reads).
// Grid 32 x 16 = 512 blocks; LDS 33.7 KB -> 4 blocks/CU = 2 waves/SIMD.
#define CHUNK 256
#define LDSLD (CHUNK + 8)   // +16B/row pad: B-reads <=~4-way bank aliasing
__global__ __launch_bounds__(128) void stage2_kernel(const bf16_t* __restrict__ eb,
                                                     const bf16_t* __restrict__ w2t,
                                                     const float* __restrict__ b2,
                                                     float* __restrict__ out) {
  __shared__ bf16_t ldsb[E_ * LDSLD];
  const int tid = threadIdx.x;
  const int lane = tid & 63;
  const int wid = tid >> 6;            // 0..1
  const int b0 = blockIdx.y * 2;
  const int t0 = blockIdx.x * 32;
  const int l15 = lane & 15;
  const int g = lane >> 4;
  // A frag: m = lane&15 (token), k = g*8 + j ; f = kk*32+k -> d = 2kk+(g>>1), w = (g&1)*8+j
  const int t = t0 + wid * 16 + l15;
  const int te = (t < T_) ? t : (T_ - 1);
  const int woff = (g & 1) * 8;
  const size_t ebase0 = ((size_t)b0 << 18);           // b0 * E_ * S_
  const size_t ebase1 = ebase0 + ((size_t)1 << 18);
  const float bb = b2[l15 * 1 + 0 * 0 + (0)];         // placeholder overwritten below
  f32x4 acc[2][4];
#pragma unroll
  for (int nt = 0; nt < 4; ++nt) {
    const float bv = b2[nt * 16 + l15];
#pragma unroll
    for (int r = 0; r < 4; ++r) { acc[0][nt][r] = bv; acc[1][nt][r] = bv; }
  }
  (void)bb;
  for (int c = 0; c < 4; ++c) {
    __syncthreads();
    // stage W2T chunk c: 64 rows x 256 bf16; 128 threads x 16 iters x 16B
    for (int i = tid; i < E_ * 32; i += 128) {
      const int row = i >> 5, seg = i & 31;
      *reinterpret_cast<bf16x8*>(&ldsb[row * LDSLD + seg * 8]) =
          *reinterpret_cast<const bf16x8*>(&w2t[row * 1024 + c * CHUNK + seg * 8]);
    }
    __syncthreads();
#pragma unroll
    for (int k8 = 0; k8 < 8; ++k8) {
      const int kk = c * 8 + k8;
      const int d = 2 * kk + (g >> 1);
      const size_t eoff = ((size_t)d << 12) + 4 * te + woff;
      const uint64_t* ap0 = reinterpret_cast<const uint64_t*>(eb + ebase0 + eoff);
      const uint64_t* ap1 = reinterpret_cast<const uint64_t*>(eb + ebase1 + eoff);
      union { uint64_t q[2]; bf16x8 v; } a0, a1;
      a0.q[0] = ap0[0]; a0.q[1] = ap0[1];
      a1.q[0] = ap1[0]; a1.q[1] = ap1[1];
      const int fb = k8 * 32 + g * 8;
#pragma unroll
      for (int nt = 0; nt < 4; ++nt) {
        const bf16x8 bfrag = *reinterpret_cast<const bf16x8*>(
            &ldsb[(nt * 16 + l15) * LDSLD + fb]);
        acc[0][nt] = __builtin_amdgcn_mfma_f32_16x16x32_bf16(a0.v, bfrag, acc[0][nt], 0, 0, 0);
        acc[1][nt] = __builtin_amdgcn_mfma_f32_16x16x32_bf16(a1.v, bfrag, acc[1][nt], 0, 0, 0);
      }
    }
  }
  // epilogue: D layout col = lane&15 (n), row = g*4 + r (token)
#pragma unroll
  for (int nt = 0; nt < 4; ++nt) {
    const int n = nt * 16 + l15;
#pragma unroll
    for (int r = 0; r < 4; ++r) {
      const int tt = t0 + wid * 16 + g * 4 + r;
      if (tt < T_) {
        out[((size_t)(b0 * T_ + tt)) * E_ + n]       = floorf(acc[0][nt][r]);
        out[((size_t)((b0 + 1) * T_ + tt)) * E_ + n] = floorf(acc[1][nt][r]);
      }
    }
  }
}

extern "C" void kernel_launch(void* const* d_in, const int* in_sizes, int n_in,
                              void* d_out, int out_size, void* d_ws, size_t ws_size,
                              hipStream_t stream) {
  const float* x  = (const float*)d_in[0];
  const float* W1 = (const float*)d_in[1];
  const float* b1 = (const float*)d_in[2];
  const float* W2 = (const float*)d_in[3];
  const float* b2 = (const float*)d_in[4];
  float* out = (float*)d_out;

  bf16_t* eb  = (bf16_t*)d_ws;                        // [B][E][S] bf16 = 16 MiB
  bf16_t* w2t = eb + (size_t)B_ * E_ * S_;            // [E][WIN*E] bf16 = 128 KiB

  hipLaunchKernelGGL(stage1_kernel, dim3(S_ / 256 + 1, B_), dim3(256), 0, stream,
                     x, W1, b1, W2, eb, w2t);
  hipLaunchKernelGGL(stage2_kernel, dim3(T_ / 32 + 1, B_ / 2), dim3(128), 0, stream,
                     eb, w2t, b2, out);
}

// Round 4
// 31.146 us; speedup vs baseline: 1.5935x; 1.5935x over previous
//
#include <hip/hip_runtime.h>
#include <cstdint>
#include <cstddef>

#define B_ 32
#define V_ 8
#define S_ 4096
#define E_ 64
#define WIN_ 16
#define STEP_ 4
#define T_ 1020   // len(arange(0, S-WIN, STEP))

typedef __bf16 bf16_t;
typedef bf16_t bf16x8 __attribute__((ext_vector_type(8)));
typedef float f32x4 __attribute__((ext_vector_type(4)));

// ---------------- stage 1 (+ fused W2 prep) ----------------
// e[b][d][s] = floor(sum_v x[b][v][s]*W1[v][d] + b1[d]), bf16, layout [B][E][S].
// Blocks with blockIdx.x==16 convert W2 -> W2T[n][f] bf16 instead.
__global__ __launch_bounds__(256) void stage1_kernel(const float* __restrict__ x,
                                                     const float* __restrict__ W1,
                                                     const float* __restrict__ b1,
                                                     const float* __restrict__ W2,
                                                     bf16_t* __restrict__ eb,
                                                     bf16_t* __restrict__ w2t) {
  const int tid = threadIdx.x;
  if (blockIdx.x == 16) {
    const int i0 = blockIdx.y * 2048 + tid * 8;   // 65536 elems over 32 y-blocks
    const int n = i0 >> 10, f0 = i0 & 1023;
    bf16x8 v;
#pragma unroll
    for (int j = 0; j < 8; ++j) v[j] = (bf16_t)W2[(f0 + j) * E_ + n];
    *reinterpret_cast<bf16x8*>(w2t + i0) = v;
    return;
  }
  __shared__ float w1s[V_ * E_];
  __shared__ float b1s[E_];
  __shared__ bf16_t tile[E_ * 256];   // [d][s_local]
  const int b = blockIdx.y;
  const int s0 = blockIdx.x * 256;
  for (int i = tid; i < V_ * E_; i += 256) w1s[i] = W1[i];
  if (tid < E_) b1s[tid] = b1[tid];
  __syncthreads();
  const int s = s0 + tid;
  float xv[V_];
#pragma unroll
  for (int v = 0; v < V_; ++v) xv[v] = x[((size_t)(b * V_ + v) << 12) + s];
  for (int d = 0; d < E_; ++d) {
    float acc = b1s[d];
#pragma unroll
    for (int v = 0; v < V_; ++v) acc += xv[v] * w1s[v * E_ + d];
    tile[d * 256 + tid] = (bf16_t)floorf(acc);
  }
  __syncthreads();
  for (int i = tid; i < E_ * 32; i += 256) {
    const int row = i >> 5, seg = i & 31;
    *reinterpret_cast<bf16x8*>(eb + (((size_t)(b * E_ + row)) << 12) + s0 + seg * 8) =
        *reinterpret_cast<const bf16x8*>(tile + row * 256 + seg * 8);
  }
}

// ---------------- stage 2 ----------------
// tokens[b][t][n] = floor(sum_f flat[b,t,f]*W2[f,n] + b2[n]); flat[b,t,f] = e[b, f>>4, 4t+(f&15)].
// 256 thr = 4 waves; block tile = 32 tokens x 64 n. Wave (mt, nh): 16 tok x 32 n quadrant.
// Grid (32,32) = 1024 blocks -> 4 blocks/CU (LDS 33 KB) = 4 waves/SIMD.
// K = 1024 in 4 chunks of 256; chunk c+1 global->reg issued before compute(c) (T14 split).
#define CHUNK 256
#define LDSLD (CHUNK + 8)   // row stride 132 dwords == 4 mod 32 -> B-reads hit 8-clk min
__global__ __launch_bounds__(256) void stage2_kernel(const bf16_t* __restrict__ eb,
                                                     const bf16_t* __restrict__ w2t,
                                                     const float* __restrict__ b2,
                                                     float* __restrict__ out) {
  __shared__ bf16_t ldsb[E_ * LDSLD];
  const int tid = threadIdx.x;
  const int lane = tid & 63;
  const int wid = tid >> 6;            // 0..3
  const int mt = wid >> 1;             // m-tile (16 tokens)
  const int nh = wid & 1;              // n-half (32 n)
  const int b = blockIdx.y;
  const int t0 = blockIdx.x * 32;
  const int l15 = lane & 15;
  const int g = lane >> 4;
  // A frag: m = l15 (token), k = g*8+j ; f = kk*32+k -> d = 2kk+(g>>1), w = (g&1)*8+j
  const int t = t0 + mt * 16 + l15;
  const int te = (t < T_) ? t : (T_ - 1);
  const int woff = (g & 1) * 8;
  const size_t ebase = ((size_t)b << 18);
  f32x4 acc[2];
#pragma unroll
  for (int nt = 0; nt < 2; ++nt) {
    const float bv = b2[nh * 32 + nt * 16 + l15];
#pragma unroll
    for (int r = 0; r < 4; ++r) acc[nt][r] = bv;
  }
  // per-thread staging slots: iter j covers elem i = tid + j*256 of the 64x256 chunk
  const int srow = tid >> 5;           // rows srow, srow+8, ... srow+56
  const int sseg = tid & 31;
  bf16x8 sreg[8];
  // stage chunk 0
#pragma unroll
  for (int j = 0; j < 8; ++j)
    sreg[j] = *reinterpret_cast<const bf16x8*>(&w2t[(srow + j * 8) * 1024 + sseg * 8]);
#pragma unroll
  for (int j = 0; j < 8; ++j)
    *reinterpret_cast<bf16x8*>(&ldsb[(srow + j * 8) * LDSLD + sseg * 8]) = sreg[j];
  __syncthreads();
  for (int c = 0; c < 4; ++c) {
    if (c < 3) {   // issue next chunk's loads early; latency hides under compute
#pragma unroll
      for (int j = 0; j < 8; ++j)
        sreg[j] = *reinterpret_cast<const bf16x8*>(
            &w2t[(srow + j * 8) * 1024 + (c + 1) * CHUNK + sseg * 8]);
    }
#pragma unroll
    for (int k8 = 0; k8 < 8; ++k8) {
      const int kk = c * 8 + k8;
      const int d = 2 * kk + (g >> 1);
      const uint64_t* ap = reinterpret_cast<const uint64_t*>(
          eb + ebase + ((size_t)d << 12) + 4 * te + woff);
      union { uint64_t q[2]; bf16x8 v; } au;
      au.q[0] = ap[0];
      au.q[1] = ap[1];
      const int fb = k8 * 32 + g * 8;
#pragma unroll
      for (int nt = 0; nt < 2; ++nt) {
        const bf16x8 bfrag = *reinterpret_cast<const bf16x8*>(
            &ldsb[(nh * 32 + nt * 16 + l15) * LDSLD + fb]);
        acc[nt] = __builtin_amdgcn_mfma_f32_16x16x32_bf16(au.v, bfrag, acc[nt], 0, 0, 0);
      }
    }
    __syncthreads();
    if (c < 3) {
#pragma unroll
      for (int j = 0; j < 8; ++j)
        *reinterpret_cast<bf16x8*>(&ldsb[(srow + j * 8) * LDSLD + sseg * 8]) = sreg[j];
      __syncthreads();
    }
  }
  // epilogue: D layout col = l15 (n), row = g*4 + r (token)
#pragma unroll
  for (int nt = 0; nt < 2; ++nt) {
    const int n = nh * 32 + nt * 16 + l15;
#pragma unroll
    for (int r = 0; r < 4; ++r) {
      const int tt = t0 + mt * 16 + g * 4 + r;
      if (tt < T_) out[((size_t)(b * T_ + tt)) * E_ + n] = floorf(acc[nt][r]);
    }
  }
}

extern "C" void kernel_launch(void* const* d_in, const int* in_sizes, int n_in,
                              void* d_out, int out_size, void* d_ws, size_t ws_size,
                              hipStream_t stream) {
  const float* x  = (const float*)d_in[0];
  const float* W1 = (const float*)d_in[1];
  const float* b1 = (const float*)d_in[2];
  const float* W2 = (const float*)d_in[3];
  const float* b2 = (const float*)d_in[4];
  float* out = (float*)d_out;

  bf16_t* eb  = (bf16_t*)d_ws;                        // [B][E][S] bf16 = 16 MiB
  bf16_t* w2t = eb + (size_t)B_ * E_ * S_;            // [E][WIN*E] bf16 = 128 KiB

  hipLaunchKernelGGL(stage1_kernel, dim3(S_ / 256 + 1, B_), dim3(256), 0, stream,
                     x, W1, b1, W2, eb, w2t);
  hipLaunchKernelGGL(stage2_kernel, dim3((T_ + 31) / 32, B_), dim3(256), 0, stream,
                     eb, w2t, b2, out);
}

// Round 5
// 23.038 us; speedup vs baseline: 2.1544x; 1.3520x over previous
//
#include <hip/hip_runtime.h>
#include <cstdint>
#include <cstddef>

#define B_ 32
#define V_ 8
#define S_ 4096
#define E_ 64
#define T_ 1020     // len(arange(0, S-WIN, STEP))
#define TT 32       // tokens per block
#define SLP 144     // padded s-extent of per-block e-tile (need 4*31+16 = 140)

typedef __bf16 bf16_t;
typedef bf16_t bf16x8 __attribute__((ext_vector_type(8)));
typedef float f32x4 __attribute__((ext_vector_type(4)));

// ---- prep: w2sw swizzled bf16 so a wave's B-fragment is one coalesced 1KB load ----
// elem index i = ((kk*4 + nt)*64 + l)*8 + j  holds  W2[f = kk*32 + (l>>4)*8 + j][n = nt*16 + (l&15)]
__global__ __launch_bounds__(256) void prep_kernel(const float* __restrict__ W2,
                                                   bf16_t* __restrict__ w2sw) {
  const int q = blockIdx.x * 256 + threadIdx.x;      // 8192 quads of 8 elems
  const int l = q & 63, nt = (q >> 6) & 3, kk = q >> 8;
  const int fb = kk * 32 + (l >> 4) * 8;
  const int n = nt * 16 + (l & 15);
  bf16x8 v;
#pragma unroll
  for (int j = 0; j < 8; ++j) v[j] = (bf16_t)W2[(fb + j) * E_ + n];
  *reinterpret_cast<bf16x8*>(w2sw + (size_t)q * 8) = v;
}

// ---- fused: per-block e-tile build (LDS) + barrier-free MFMA K-loop ----
// Block (t0, b): 32 tokens x 64 n, 4 waves; wave wv owns n in [wv*16, wv*16+16), 32 tokens.
// A-frag (mt): lane(l15,g): token = mt*16+l15, k = g*8+j -> e[d = 2kk+(g>>1)][s_local = 4*(mt*16+l15) + (g&1)*8 + j]
__global__ __launch_bounds__(256, 4) void fused_kernel(const float* __restrict__ x,
                                                       const float* __restrict__ W1,
                                                       const float* __restrict__ b1,
                                                       const bf16_t* __restrict__ w2sw,
                                                       const float* __restrict__ b2,
                                                       float* __restrict__ out) {
  __shared__ float w1s[V_ * E_];
  __shared__ float b1s[E_];
  __shared__ bf16_t et[E_ * SLP];
  const int tid = threadIdx.x;
  const int b = blockIdx.y;
  const int t0 = blockIdx.x * TT;
  for (int i = tid; i < V_ * E_; i += 256) w1s[i] = W1[i];
  if (tid < E_) b1s[tid] = b1[tid];
  __syncthreads();
  // ---- e-tile build: 64 d x 140 s_local; thread = (d-half, s_local), 2 s-slots ----
  {
    const int dbase = (tid >> 7) * 32;    // 0 or 32
    const int sl = tid & 127;
    const int s0 = 4 * t0;
    int s_a = s0 + sl;        if (s_a > S_ - 1) s_a = S_ - 1;   // clamp: only invalid tokens touch it
    int s_b = s0 + sl + 128;  if (s_b > S_ - 1) s_b = S_ - 1;
    const bool has2 = (sl + 128) < 140;
    float xv0[V_], xv1[V_];
#pragma unroll
    for (int v = 0; v < V_; ++v) {
      xv0[v] = x[((size_t)(b * V_ + v) << 12) + s_a];
      xv1[v] = x[((size_t)(b * V_ + v) << 12) + s_b];
    }
    for (int d = dbase; d < dbase + 32; ++d) {
      float a0 = b1s[d], a1 = b1s[d];
#pragma unroll
      for (int v = 0; v < V_; ++v) {
        a0 += xv0[v] * w1s[v * E_ + d];
        a1 += xv1[v] * w1s[v * E_ + d];
      }
      et[d * SLP + sl] = (bf16_t)floorf(a0);
      if (has2) et[d * SLP + sl + 128] = (bf16_t)floorf(a1);
    }
  }
  __syncthreads();
  // ---- K-loop: no barriers; A from LDS e-tile, B coalesced-streamed from w2sw ----
  const int lane = tid & 63;
  const int wv = tid >> 6;              // n-quarter 0..3
  const int l15 = lane & 15;
  const int g = lane >> 4;
  const char* etb = reinterpret_cast<const char*>(et);
  const uint32_t aoff = 288u * (g >> 1) + 8u * l15 + 16u * (g & 1);  // + 576*kk + 128*mt bytes
  const bf16_t* bptr = w2sw + (((size_t)wv * 64 + lane) << 3);       // + kk*2048 elems
  const float bv = b2[wv * 16 + l15];
  f32x4 acc0 = {bv, bv, bv, bv};
  f32x4 acc1 = {bv, bv, bv, bv};
#pragma unroll 4
  for (int kk = 0; kk < 32; ++kk) {
    const char* pa = etb + aoff + 576 * kk;
    union { uint64_t q[2]; bf16x8 v; } A0, A1;
    A0.q[0] = *reinterpret_cast<const uint64_t*>(pa);
    A0.q[1] = *reinterpret_cast<const uint64_t*>(pa + 8);
    A1.q[0] = *reinterpret_cast<const uint64_t*>(pa + 128);
    A1.q[1] = *reinterpret_cast<const uint64_t*>(pa + 136);
    const bf16x8 Bf = *reinterpret_cast<const bf16x8*>(bptr + ((size_t)kk << 11));
    acc0 = __builtin_amdgcn_mfma_f32_16x16x32_bf16(A0.v, Bf, acc0, 0, 0, 0);
    acc1 = __builtin_amdgcn_mfma_f32_16x16x32_bf16(A1.v, Bf, acc1, 0, 0, 0);
  }
  // ---- epilogue: D row = g*4+r (token), col = l15 (n) ----
#pragma unroll
  for (int r = 0; r < 4; ++r) {
    const int t1 = t0 + g * 4 + r;
    if (t1 < T_) out[((size_t)(b * T_ + t1)) * E_ + wv * 16 + l15] = floorf(acc0[r]);
    const int t2 = t0 + 16 + g * 4 + r;
    if (t2 < T_) out[((size_t)(b * T_ + t2)) * E_ + wv * 16 + l15] = floorf(acc1[r]);
  }
}

extern "C" void kernel_launch(void* const* d_in, const int* in_sizes, int n_in,
                              void* d_out, int out_size, void* d_ws, size_t ws_size,
                              hipStream_t stream) {
  const float* x  = (const float*)d_in[0];
  const float* W1 = (const float*)d_in[1];
  const float* b1 = (const float*)d_in[2];
  const float* W2 = (const float*)d_in[3];
  const float* b2 = (const float*)d_in[4];
  float* out = (float*)d_out;

  bf16_t* w2sw = (bf16_t*)d_ws;   // 128 KiB swizzled bf16 W2

  hipLaunchKernelGGL(prep_kernel, dim3(32), dim3(256), 0, stream, W2, w2sw);
  hipLaunchKernelGGL(fused_kernel, dim3((T_ + TT - 1) / TT, B_), dim3(256), 0, stream,
                     x, W1, b1, w2sw, b2, out);
}

// Round 6
// 21.347 us; speedup vs baseline: 2.3251x; 1.0792x over previous
//
#include <hip/hip_runtime.h>
#include <cstdint>
#include <cstddef>

#define B_ 32
#define V_ 8
#define S_ 4096
#define E_ 64
#define T_ 1020     // len(arange(0, S-WIN, STEP))
#define TT 32       // tokens per block
#define SLP 200     // e-tile row stride (need >=140 cols; 400B = 100dw = 4 mod 32 -> pad-friendly)

typedef __bf16 bf16_t;
typedef bf16_t bf16x8 __attribute__((ext_vector_type(8)));
typedef float f32x4 __attribute__((ext_vector_type(4)));

// ---- prep: w2sw swizzled bf16 so a wave's B-fragment is one coalesced 1KB load ----
// elem index i = ((kk*4 + nt)*64 + l)*8 + j  holds  W2[f = kk*32 + (l>>4)*8 + j][n = nt*16 + (l&15)]
__global__ __launch_bounds__(256) void prep_kernel(const float* __restrict__ W2,
                                                   bf16_t* __restrict__ w2sw) {
  const int q = blockIdx.x * 256 + threadIdx.x;      // 8192 quads of 8 elems
  const int l = q & 63, nt = (q >> 6) & 3, kk = q >> 8;
  const int fb = kk * 32 + (l >> 4) * 8;
  const int n = nt * 16 + (l & 15);
  bf16x8 v;
#pragma unroll
  for (int j = 0; j < 8; ++j) v[j] = (bf16_t)W2[(fb + j) * E_ + n];
  *reinterpret_cast<bf16x8*>(w2sw + (size_t)q * 8) = v;
}

// ---- fused: per-block e-tile build (LDS) + barrier-free MFMA K-loop ----
// Block (t0, b): 32 tokens x 64 n, 4 waves; wave wv owns n quarter, 32 tokens.
__global__ __launch_bounds__(256, 4) void fused_kernel(const float* __restrict__ x,
                                                       const float* __restrict__ W1,
                                                       const float* __restrict__ b1,
                                                       const bf16_t* __restrict__ w2sw,
                                                       const float* __restrict__ b2,
                                                       float* __restrict__ out) {
  __shared__ bf16_t et[E_ * SLP];   // 25.6 KB
  const int tid = threadIdx.x;
  const int b = blockIdx.y;
  const int t0 = blockIdx.x * TT;
  // ---- e-build: thread = (d-group dg of 8 d, s-lane sg) x 5 s-slots ----
  // W1/b1 read direct from global (L1 broadcast, off the LDS pipe); x in VGPRs.
  {
    const int dg = tid >> 5;            // 0..7
    const int sg = tid & 31;
    const int s0 = 4 * t0;
    float xv[V_][5];
#pragma unroll
    for (int v = 0; v < V_; ++v) {
#pragma unroll
      for (int k = 0; k < 5; ++k) {
        int s = s0 + sg + 32 * k;       // covers s_local 0..159 (need 0..139)
        if (s > S_ - 1) s = S_ - 1;     // clamp: only masked-token region affected
        xv[v][k] = x[((size_t)(b * V_ + v) << 12) + s];
      }
    }
#pragma unroll
    for (int dd = 0; dd < 8; ++dd) {
      const int d = dg * 8 + dd;
      const float bb = b1[d];
      float acc[5];
#pragma unroll
      for (int k = 0; k < 5; ++k) acc[k] = bb;
#pragma unroll
      for (int v = 0; v < V_; ++v) {
        const float w = W1[v * E_ + d];   // loaded once, reused over 5 slots
#pragma unroll
        for (int k = 0; k < 5; ++k) acc[k] += xv[v][k] * w;
      }
#pragma unroll
      for (int k = 0; k < 5; ++k)
        et[d * SLP + sg + 32 * k] = (bf16_t)floorf(acc[k]);
    }
  }
  __syncthreads();
  // ---- K-loop: no barriers; A from LDS e-tile, B coalesced-streamed from w2sw ----
  const int lane = tid & 63;
  const int wv = tid >> 6;              // n-quarter 0..3
  const int l15 = lane & 15;
  const int g = lane >> 4;
  const char* etb = reinterpret_cast<const char*>(et);
  // A-frag byte offset: d = 2kk + (g>>1) (row stride 400B), s_local = 4*(mt*16+l15) + 8*(g&1)
  const uint32_t aoff = 400u * (g >> 1) + 8u * l15 + 16u * (g & 1);  // +800/kk, +128/mt
  const bf16_t* bptr = w2sw + (((size_t)wv * 64 + lane) << 3);       // +2048 elems per kk
  const float bv = b2[wv * 16 + l15];
  f32x4 acc0 = {bv, bv, bv, bv};
  f32x4 acc1 = {bv, bv, bv, bv};
#pragma unroll 4
  for (int kk = 0; kk < 32; ++kk) {
    const char* pa = etb + aoff + 800 * kk;
    union { uint64_t q[2]; bf16x8 v; } A0, A1;
    A0.q[0] = *reinterpret_cast<const uint64_t*>(pa);
    A0.q[1] = *reinterpret_cast<const uint64_t*>(pa + 8);
    A1.q[0] = *reinterpret_cast<const uint64_t*>(pa + 128);
    A1.q[1] = *reinterpret_cast<const uint64_t*>(pa + 136);
    const bf16x8 Bf = *reinterpret_cast<const bf16x8*>(bptr + ((size_t)kk << 11));
    acc0 = __builtin_amdgcn_mfma_f32_16x16x32_bf16(A0.v, Bf, acc0, 0, 0, 0);
    acc1 = __builtin_amdgcn_mfma_f32_16x16x32_bf16(A1.v, Bf, acc1, 0, 0, 0);
  }
  // ---- epilogue: D row = g*4+r (token), col = l15 (n) ----
#pragma unroll
  for (int r = 0; r < 4; ++r) {
    const int t1 = t0 + g * 4 + r;
    if (t1 < T_) out[((size_t)(b * T_ + t1)) * E_ + wv * 16 + l15] = floorf(acc0[r]);
    const int t2 = t0 + 16 + g * 4 + r;
    if (t2 < T_) out[((size_t)(b * T_ + t2)) * E_ + wv * 16 + l15] = floorf(acc1[r]);
  }
}

extern "C" void kernel_launch(void* const* d_in, const int* in_sizes, int n_in,
                              void* d_out, int out_size, void* d_ws, size_t ws_size,
                              hipStream_t stream) {
  const float* x  = (const float*)d_in[0];
  const float* W1 = (const float*)d_in[1];
  const float* b1 = (const float*)d_in[2];
  const float* W2 = (const float*)d_in[3];
  const float* b2 = (const float*)d_in[4];
  float* out = (float*)d_out;

  bf16_t* w2sw = (bf16_t*)d_ws;   // 128 KiB swizzled bf16 W2

  hipLaunchKernelGGL(prep_kernel, dim3(32), dim3(256), 0, stream, W2, w2sw);
  hipLaunchKernelGGL(fused_kernel, dim3((T_ + TT - 1) / TT, B_), dim3(256), 0, stream,
                     x, W1, b1, w2sw, b2, out);
}